// Round 1
// baseline (86.626 us; speedup 1.0000x reference)
//
#include <hip/hip_runtime.h>
#include <math.h>

// Reference collapses to: out[b] = MLP( softmax-weighted sum over t of v[b,t] )
// using only s=0 of the attention output (reference returns y[0,:,0]).
// S=2048, B=32, H=1, MLP_HID=256, OUT_DIM=1.

constexpr int S   = 2048;
constexpr int B   = 32;
constexpr int TPB = 256;      // threads per block
constexpr int TPT = S / TPB;  // 8 t-values per thread

__global__ __launch_bounds__(TPB) void fused_transformer_row0(
    const float* __restrict__ src,   // [S, B]
    const float* __restrict__ Wq, const float* __restrict__ bq,
    const float* __restrict__ Wk, const float* __restrict__ bk,
    const float* __restrict__ Wv, const float* __restrict__ bv,
    const float* __restrict__ bias,  // [1, S, S]; we use bias[0,0,t] = bias[t]
    const float* __restrict__ W1,    // [256,1] flat
    const float* __restrict__ b1,    // [256]
    const float* __restrict__ W2,    // [1,256] flat
    const float* __restrict__ b2,    // [1]
    float* __restrict__ out)         // [B]
{
    const int b    = blockIdx.x;     // batch element
    const int tid  = threadIdx.x;
    const int lane = tid & 63;
    const int wave = tid >> 6;

    __shared__ float red_m[4];
    __shared__ float red_l[4];
    __shared__ float red_c[4];
    __shared__ float red_y[4];

    const float wq  = Wq[0], wk = Wk[0], wv = Wv[0];
    const float bk0 = bk[0], bv0 = bv[0];
    // q at s=0 for this batch element
    const float qb = src[0 * B + b] * wq + bq[0];

    // Per-thread: scores and v for 8 t positions
    float sc[TPT], vv[TPT];
    float mloc = -INFINITY;
#pragma unroll
    for (int i = 0; i < TPT; ++i) {
        const int t = tid + i * TPB;
        const float x = src[t * B + b];
        sc[i] = qb * (x * wk + bk0) + bias[t];   // bias[0,0,t]
        vv[i] = x * wv + bv0;
        mloc  = fmaxf(mloc, sc[i]);
    }

    // Block max reduction (wave shuffle width 64, then LDS across 4 waves)
#pragma unroll
    for (int off = 32; off > 0; off >>= 1)
        mloc = fmaxf(mloc, __shfl_down(mloc, off, 64));
    if (lane == 0) red_m[wave] = mloc;
    __syncthreads();
    const float gmax = fmaxf(fmaxf(red_m[0], red_m[1]), fmaxf(red_m[2], red_m[3]));

    // exp-sum and weighted v-sum
    float lsum = 0.f, csum = 0.f;
#pragma unroll
    for (int i = 0; i < TPT; ++i) {
        const float e = __expf(sc[i] - gmax);
        lsum += e;
        csum += e * vv[i];
    }
#pragma unroll
    for (int off = 32; off > 0; off >>= 1) {
        lsum += __shfl_down(lsum, off, 64);
        csum += __shfl_down(csum, off, 64);
    }
    if (lane == 0) { red_l[wave] = lsum; red_c[wave] = csum; }
    __syncthreads();
    const float L = red_l[0] + red_l[1] + red_l[2] + red_l[3];
    const float C = red_c[0] + red_c[1] + red_c[2] + red_c[3];
    const float ctx = C / L;

    // MLP: thread tid computes hidden unit tid (MLP_HID == TPB == 256)
    float h = fmaxf(ctx * W1[tid] + b1[tid], 0.f);
    float term = h * W2[tid];
#pragma unroll
    for (int off = 32; off > 0; off >>= 1)
        term += __shfl_down(term, off, 64);
    __syncthreads();               // protect red_y reuse ordering vs reads above
    if (lane == 0) red_y[wave] = term;
    __syncthreads();
    if (tid == 0)
        out[b] = red_y[0] + red_y[1] + red_y[2] + red_y[3] + b2[0];
}

extern "C" void kernel_launch(void* const* d_in, const int* in_sizes, int n_in,
                              void* d_out, int out_size, void* d_ws, size_t ws_size,
                              hipStream_t stream) {
    const float* src  = (const float*)d_in[0];
    const float* Wq   = (const float*)d_in[1];
    const float* bq   = (const float*)d_in[2];
    const float* Wk   = (const float*)d_in[3];
    const float* bk   = (const float*)d_in[4];
    const float* Wv   = (const float*)d_in[5];
    const float* bv   = (const float*)d_in[6];
    const float* bias = (const float*)d_in[7];
    const float* W1   = (const float*)d_in[8];
    const float* b1   = (const float*)d_in[9];
    const float* W2   = (const float*)d_in[10];
    const float* b2   = (const float*)d_in[11];
    float* out = (float*)d_out;

    fused_transformer_row0<<<B, TPB, 0, stream>>>(
        src, Wq, bq, Wk, bk, Wv, bv, bias, W1, b1, W2, b2, out);
}